// Round 4
// baseline (152.427 us; speedup 1.0000x reference)
//
#include <hip/hip_runtime.h>
#include <hip/hip_bf16.h>

typedef __bf16 bf16;
typedef bf16 bf16x4 __attribute__((ext_vector_type(4)));
typedef bf16 bf16x8 __attribute__((ext_vector_type(8)));
typedef float f32x4 __attribute__((ext_vector_type(4)));

#define GLOAD16(g, l) __builtin_amdgcn_global_load_lds( \
    (const __attribute__((address_space(1))) void*)(g),  \
    (__attribute__((address_space(3))) void*)(l), 16, 0, 0)

#define EXP2F(x) __builtin_amdgcn_exp2f(x)
#define MFMA16(a, b, c) __builtin_amdgcn_mfma_f32_16x16x32_bf16(a, b, c, 0, 0, 0)

// ---------------- cast fp32 -> bf16, 8 elems/thread ----------------
__global__ __launch_bounds__(256) void cast_f32_bf16(const float* __restrict__ in,
                                                     bf16* __restrict__ out, int n8) {
  int i = blockIdx.x * 256 + threadIdx.x;
  if (i >= n8) return;
  const float4* p = (const float4*)in + (size_t)i * 2;
  float4 a = p[0], b = p[1];
  bf16x8 o;
  o[0] = (bf16)a.x; o[1] = (bf16)a.y; o[2] = (bf16)a.z; o[3] = (bf16)a.w;
  o[4] = (bf16)b.x; o[5] = (bf16)b.y; o[6] = (bf16)b.z; o[7] = (bf16)b.w;
  ((bf16x8*)out)[i] = o;
}

// ------------- transpose+cast: src[K][N] f32 -> dst[N][K] bf16 -------------
__global__ __launch_bounds__(256) void transpose_cast(const float* __restrict__ src,
                                                      bf16* __restrict__ dst,
                                                      int K, int N) {
  __shared__ float tile[32][33];
  int n0 = blockIdx.x * 32, k0 = blockIdx.y * 32;
  int tx = threadIdx.x, ty = threadIdx.y;  // 32 x 8
#pragma unroll
  for (int i = 0; i < 4; i++)
    tile[ty + 8 * i][tx] = src[(size_t)(k0 + ty + 8 * i) * N + n0 + tx];
  __syncthreads();
#pragma unroll
  for (int i = 0; i < 4; i++)
    dst[(size_t)(n0 + ty + 8 * i) * K + k0 + tx] = (bf16)tile[tx][ty + 8 * i];
}

// =================== 256x256-tile GEMM, 3-stage pipeline ===================
// C[256,256]/block = A[4096,1024] x Bt[3072,1024]^T tile. 512 thr = 8 waves
// (2M x 4N), wave tile 128x64, BK=32. 3 rotating K-tile buffers; iter j
// computes kt j (buf j%3), stages kt j+2 (buf (j+2)%3); counted vmcnt(4)
// (next-next tile in flight) + ONE raw barrier per iter. LDS rows 64B with
// chunk-XOR swizzle (chunk ^= (row>>1)&3): frag reads 2-way max (free).
__global__ __launch_bounds__(512, 2) void gemm256_qkv(const bf16* __restrict__ A,
                                                      const bf16* __restrict__ Bt,
                                                      bf16* __restrict__ q,
                                                      bf16* __restrict__ kk,
                                                      bf16* __restrict__ vt) {
  __shared__ bf16 As[3][256 * 32];   // 48 KB
  __shared__ bf16 Bs[3][256 * 32];   // 48 KB
  int tid = threadIdx.x, lane = tid & 63;
  int w = tid >> 6, wr = w >> 2, wc = w & 3;
  int c16 = lane & 15, g = lane >> 4;
  const int K = 1024;
  // XCD-bijective decode: 192 = 8*24; each XCD gets 2 bm-rows (A L2 reuse)
  int id = blockIdx.x;
  int wg = (id & 7) * 24 + (id >> 3);
  int bm = wg / 12, bn = wg - bm * 12;
  int m0 = bm * 256, n0 = bn * 256;

  auto stage = [&](int kt, int b) {
#pragma unroll
    for (int i = 0; i < 2; i++) {
      int d = i * 8192 + tid * 16;          // linear LDS byte (lane-contig/wave)
      int row = d >> 6, ch = (d >> 4) & 3;
      int sc = ch ^ ((row >> 1) & 3);       // inverse swizzle on global source
      GLOAD16(A + (size_t)(m0 + row) * K + kt * 32 + sc * 8, (char*)As[b] + d);
    }
#pragma unroll
    for (int i = 0; i < 2; i++) {
      int d = i * 8192 + tid * 16;
      int row = d >> 6, ch = (d >> 4) & 3;
      int sc = ch ^ ((row >> 1) & 3);
      GLOAD16(Bt + (size_t)(n0 + row) * K + kt * 32 + sc * 8, (char*)Bs[b] + d);
    }
  };

  // swizzled frag byte-offsets
  int aoff[8], boff[4];
#pragma unroll
  for (int mi = 0; mi < 8; mi++) {
    int ar = wr * 128 + mi * 16 + c16;
    aoff[mi] = ar * 64 + ((g ^ ((ar >> 1) & 3)) << 4);
  }
#pragma unroll
  for (int ni = 0; ni < 4; ni++) {
    int br = wc * 64 + ni * 16 + c16;
    boff[ni] = br * 64 + ((g ^ ((br >> 1) & 3)) << 4);
  }

  f32x4 acc[8][4];
  {
    f32x4 z = {0.f, 0.f, 0.f, 0.f};
#pragma unroll
    for (int mi = 0; mi < 8; mi++)
#pragma unroll
      for (int ni = 0; ni < 4; ni++) acc[mi][ni] = z;
  }

  stage(0, 0);
  stage(1, 1);
  asm volatile("s_waitcnt vmcnt(4)" ::: "memory");   // kt0 resident, kt1 in flight
  __builtin_amdgcn_s_barrier();
  __builtin_amdgcn_sched_barrier(0);

  for (int j = 0; j < 32; ++j) {
    if (j + 2 < 32) stage(j + 2, (j + 2) % 3);
    const char* Ab = (const char*)As[j % 3];
    const char* Bb = (const char*)Bs[j % 3];
    bf16x8 bf[4], af[4];
#pragma unroll
    for (int ni = 0; ni < 4; ni++) bf[ni] = *(const bf16x8*)(Bb + boff[ni]);
#pragma unroll
    for (int mi = 0; mi < 4; mi++) af[mi] = *(const bf16x8*)(Ab + aoff[mi]);
    __builtin_amdgcn_s_setprio(1);
#pragma unroll
    for (int mi = 0; mi < 4; mi++)
#pragma unroll
      for (int ni = 0; ni < 4; ni++)
        acc[mi][ni] = MFMA16(af[mi], bf[ni], acc[mi][ni]);
    __builtin_amdgcn_s_setprio(0);
#pragma unroll
    for (int mi = 0; mi < 4; mi++) af[mi] = *(const bf16x8*)(Ab + aoff[4 + mi]);
    __builtin_amdgcn_s_setprio(1);
#pragma unroll
    for (int mi = 0; mi < 4; mi++)
#pragma unroll
      for (int ni = 0; ni < 4; ni++)
        acc[4 + mi][ni] = MFMA16(af[mi], bf[ni], acc[4 + mi][ni]);
    __builtin_amdgcn_s_setprio(0);
    if (j + 2 < 32) {
      asm volatile("s_waitcnt vmcnt(4)" ::: "memory");  // kt j+1 done; j+2 in flight
    } else if (j + 1 < 32) {
      asm volatile("s_waitcnt vmcnt(0)" ::: "memory");  // final drain (j=30)
    }
    if (j + 1 < 32) {
      __builtin_amdgcn_s_barrier();
      __builtin_amdgcn_sched_barrier(0);
    }
  }

  // ---- QKV scatter epilogue (q pre-scaled 0.125*log2e for exp2 softmax) ----
  int which = n0 >> 10;   // block-uniform (256 | 1024)
  const float QSCALE = 0.125f * 1.4426950408889634f;
#pragma unroll
  for (int mi = 0; mi < 8; mi++)
#pragma unroll
    for (int ni = 0; ni < 4; ni++)
#pragma unroll
      for (int j = 0; j < 4; j++) {
        int gm = m0 + wr * 128 + mi * 16 + g * 4 + j;
        int gn = n0 + wc * 64 + ni * 16 + c16;
        int rem = gn & 1023, h = rem >> 6, d = rem & 63;
        int b = gm >> 11, t = gm & 2047;
        float v = acc[mi][ni][j];
        size_t bh = (size_t)(b * 16 + h);
        if (which == 0)      q[(bh * 2048 + t) * 64 + d]  = (bf16)(v * QSCALE);
        else if (which == 1) kk[(bh * 2048 + t) * 64 + d] = (bf16)v;
        else                 vt[(bh * 64 + d) * 2048 + t] = (bf16)v;
      }
}

// =================== 128x128-tile GEMM (out proj), 3-stage ===================
// grid 256 (1/CU), 256 thr = 4 waves (2x2), wave tile 64x64, BK=32.
__global__ __launch_bounds__(256, 2) void gemm_out3(const bf16* __restrict__ A,
                                                    const bf16* __restrict__ Bt,
                                                    float* __restrict__ C) {
  __shared__ bf16 As[3][128 * 32];   // 24 KB
  __shared__ bf16 Bs[3][128 * 32];   // 24 KB
  int tid = threadIdx.x, lane = tid & 63;
  int w = tid >> 6, wr = w >> 1, wc = w & 1;
  int c16 = lane & 15, g = lane >> 4;
  const int K = 1024;
  int id = blockIdx.x;
  int wg = (id & 7) * 32 + (id >> 3);   // 256 = 8*32
  int bm = wg >> 3, bn = wg & 7;
  int m0 = bm * 128, n0 = bn * 128;

  auto stage = [&](int kt, int b) {
#pragma unroll
    for (int i = 0; i < 2; i++) {
      int d = i * 4096 + tid * 16;
      int row = d >> 6, ch = (d >> 4) & 3;
      int sc = ch ^ ((row >> 1) & 3);
      GLOAD16(A + (size_t)(m0 + row) * K + kt * 32 + sc * 8, (char*)As[b] + d);
    }
#pragma unroll
    for (int i = 0; i < 2; i++) {
      int d = i * 4096 + tid * 16;
      int row = d >> 6, ch = (d >> 4) & 3;
      int sc = ch ^ ((row >> 1) & 3);
      GLOAD16(Bt + (size_t)(n0 + row) * K + kt * 32 + sc * 8, (char*)Bs[b] + d);
    }
  };

  int aoff[4], boff[4];
#pragma unroll
  for (int mi = 0; mi < 4; mi++) {
    int ar = wr * 64 + mi * 16 + c16;
    aoff[mi] = ar * 64 + ((g ^ ((ar >> 1) & 3)) << 4);
  }
#pragma unroll
  for (int ni = 0; ni < 4; ni++) {
    int br = wc * 64 + ni * 16 + c16;
    boff[ni] = br * 64 + ((g ^ ((br >> 1) & 3)) << 4);
  }

  f32x4 acc[4][4];
  {
    f32x4 z = {0.f, 0.f, 0.f, 0.f};
#pragma unroll
    for (int mi = 0; mi < 4; mi++)
#pragma unroll
      for (int ni = 0; ni < 4; ni++) acc[mi][ni] = z;
  }

  stage(0, 0);
  stage(1, 1);
  asm volatile("s_waitcnt vmcnt(4)" ::: "memory");
  __builtin_amdgcn_s_barrier();
  __builtin_amdgcn_sched_barrier(0);

  for (int j = 0; j < 32; ++j) {
    if (j + 2 < 32) stage(j + 2, (j + 2) % 3);
    const char* Ab = (const char*)As[j % 3];
    const char* Bb = (const char*)Bs[j % 3];
    bf16x8 bf[4], af[4];
#pragma unroll
    for (int ni = 0; ni < 4; ni++) bf[ni] = *(const bf16x8*)(Bb + boff[ni]);
#pragma unroll
    for (int mi = 0; mi < 4; mi++) af[mi] = *(const bf16x8*)(Ab + aoff[mi]);
    __builtin_amdgcn_s_setprio(1);
#pragma unroll
    for (int mi = 0; mi < 4; mi++)
#pragma unroll
      for (int ni = 0; ni < 4; ni++)
        acc[mi][ni] = MFMA16(af[mi], bf[ni], acc[mi][ni]);
    __builtin_amdgcn_s_setprio(0);
    if (j + 2 < 32) {
      asm volatile("s_waitcnt vmcnt(4)" ::: "memory");
    } else if (j + 1 < 32) {
      asm volatile("s_waitcnt vmcnt(0)" ::: "memory");
    }
    if (j + 1 < 32) {
      __builtin_amdgcn_s_barrier();
      __builtin_amdgcn_sched_barrier(0);
    }
  }

#pragma unroll
  for (int mi = 0; mi < 4; mi++)
#pragma unroll
    for (int ni = 0; ni < 4; ni++)
#pragma unroll
      for (int j = 0; j < 4; j++) {
        int gm = m0 + wr * 64 + mi * 16 + g * 4 + j;
        int gn = n0 + wc * 64 + ni * 16 + c16;
        C[(size_t)gm * 1024 + gn] = acc[mi][ni][j];
      }
}

// ---------------- flash attention v4 (3-stage K/V pipeline) ----------------
// 512 blocks x 512 threads (8 waves); wave w owns q rows [q0+16w, +16).
// Swapped QK^T; exp2-domain in-register softmax; defer-max. K/V in 3 rotating
// buffers: iter t computes tile t (buf t%3), prefetches tile t+2; counted
// vmcnt(2) + raw barrier per tile (no vmcnt(0) drain in steady loop).
__global__ __launch_bounds__(512) void attn(const bf16* __restrict__ q,
                                            const bf16* __restrict__ kk,
                                            const bf16* __restrict__ vt,
                                            bf16* __restrict__ out) {
  __shared__ bf16 Ks[3][64 * 64];   // 24 KB (chunk-XOR swizzled)
  __shared__ bf16 Vs[3][64 * 64];   // 24 KB (chunk-XOR swizzled)
  __shared__ bf16 PQ[128 * 64];     // 16 KB: Q staging (prologue) / P tiles
  int tid = threadIdx.x, lane = tid & 63, w = tid >> 6;
  int c16 = lane & 15, g = (lane >> 4) & 3, g4 = g * 4;

  // ---- XCD-aware decode (bijection on 512 blocks) ----
  int id = blockIdx.x;
  int c = id & 7;          // XCD
  int k = id >> 3;         // 0..63 within XCD
  int s = k >> 5;          // 0..1
  int j5 = k & 31;
  int bxi = j5 & 15, b2 = j5 >> 4;
  int bx = s ? (15 - bxi) : bxi;       // pairs (k, k+32) sum to 15
  int bh = 4 * c + 2 * b2 + s;         // 4 bh per XCD (K/V L2-resident)
  int q0 = bx * 128;

  const bf16* qb = q  + (size_t)bh * 2048 * 64;
  const bf16* kb = kk + (size_t)bh * 2048 * 64;
  const bf16* vb = vt + (size_t)bh * 64 * 2048;
  int nt = 2 * bx + 2;

  // ---- prologue: stage Q[128][64] + K/V tiles 0,1 ----
#pragma unroll
  for (int i = 0; i < 2; i++) {
    int cc = tid + i * 512;
    int r = cc >> 3, ds = (cc & 7) * 8;
    GLOAD16(qb + (size_t)(q0 + r) * 64 + ds, PQ + cc * 8);
  }
  {
    int r = tid >> 3, p = tid & 7;
    GLOAD16(kb + (size_t)r * 64 + ((p ^ (r & 7)) * 8), Ks[0] + tid * 8);
    GLOAD16(vb + (size_t)r * 2048 + ((p ^ (r & 7)) * 8), Vs[0] + tid * 8);
    GLOAD16(kb + (size_t)(64 + r) * 64 + ((p ^ (r & 7)) * 8), Ks[1] + tid * 8);
    GLOAD16(vb + (size_t)r * 2048 + 64 + ((p ^ (r & 7)) * 8), Vs[1] + tid * 8);
  }
  __syncthreads();   // drains all prologue staging
  bf16x8 qf[2];      // B-operand frag: Q[q0+16w+c16][ks*32+g*8 ..]
#pragma unroll
  for (int ks = 0; ks < 2; ks++)
    qf[ks] = *(const bf16x8*)(PQ + (w * 16 + c16) * 64 + ks * 32 + g * 8);
  __syncthreads();   // all waves done reading Q (PQ becomes P storage)

  f32x4 o[4];
  float mrun = -__builtin_inff(), lrun = 0.f;
  {
    f32x4 z = {0.f, 0.f, 0.f, 0.f};
#pragma unroll
    for (int n = 0; n < 4; n++) o[n] = z;
  }
  int qlo = q0 + w * 16;
  int qr = qlo + c16;
  bf16* Pw = PQ + w * 1024;        // 16x64 per-wave P tile

  for (int t = 0; t < nt; ++t) {
    int s0 = t * 64;
    if (t + 2 < nt) {              // prefetch tile t+2
      int sn = s0 + 128;
      int r = tid >> 3, p = tid & 7;
      int nb = (t + 2) % 3;
      GLOAD16(kb + (size_t)(sn + r) * 64 + ((p ^ (r & 7)) * 8), Ks[nb] + tid * 8);
      GLOAD16(vb + (size_t)r * 2048 + sn + ((p ^ (r & 7)) * 8), Vs[nb] + tid * 8);
    }
    int cb = t % 3;
    if (s0 <= qlo + 15) {   // wave-uniform causal skip
      // ---- QK^T: S^T = mfma(K, Q); lane holds S[q=c16][s=n*16+g4+r] ----
      f32x4 S[4];
      {
        f32x4 z = {0.f, 0.f, 0.f, 0.f};
#pragma unroll
        for (int n = 0; n < 4; n++) S[n] = z;
      }
      __builtin_amdgcn_s_setprio(1);
#pragma unroll
      for (int ks = 0; ks < 2; ks++) {
        bf16x8 kf[4];
#pragma unroll
        for (int n = 0; n < 4; n++) {
          int srow = n * 16 + c16;
          kf[n] = *(const bf16x8*)((const char*)Ks[cb] + srow * 128 +
                                   (((ks * 4 + g) ^ (srow & 7)) << 4));
        }
#pragma unroll
        for (int n = 0; n < 4; n++)
          S[n] = MFMA16(kf[n], qf[ks], S[n]);
      }
      __builtin_amdgcn_s_setprio(0);
      // ---- causal mask (diag tiles only) ----
      if (s0 + 63 > qlo) {
#pragma unroll
        for (int n = 0; n < 4; n++)
#pragma unroll
          for (int r = 0; r < 4; r++)
            if (s0 + n * 16 + g4 + r > qr) S[n][r] = -__builtin_inff();
      }
      // ---- online softmax (exp2 domain), defer-max ----
      float tm = fmaxf(fmaxf(fmaxf(S[0][0], S[0][1]), fmaxf(S[0][2], S[0][3])),
                       fmaxf(fmaxf(S[1][0], S[1][1]), fmaxf(S[1][2], S[1][3])));
      tm = fmaxf(tm, fmaxf(fmaxf(fmaxf(S[2][0], S[2][1]), fmaxf(S[2][2], S[2][3])),
                           fmaxf(fmaxf(S[3][0], S[3][1]), fmaxf(S[3][2], S[3][3]))));
      tm = fmaxf(tm, __shfl_xor(tm, 16));
      tm = fmaxf(tm, __shfl_xor(tm, 32));
      if (!__all(tm <= mrun + 8.f)) {
        float mnew = fmaxf(mrun, tm);
        float corr = EXP2F(mrun - mnew);
        lrun *= corr;
        mrun = mnew;
#pragma unroll
        for (int j = 0; j < 4; j++) {
          float cj = __shfl(corr, (lane & 48) | (g4 + j));
#pragma unroll
          for (int n = 0; n < 4; n++) o[n][j] *= cj;
        }
      }
      float p[4][4];
      float rs = 0.f;
#pragma unroll
      for (int n = 0; n < 4; n++)
#pragma unroll
        for (int r = 0; r < 4; r++) {
          p[n][r] = EXP2F(S[n][r] - mrun);
          rs += p[n][r];
        }
      rs += __shfl_xor(rs, 16);
      rs += __shfl_xor(rs, 32);
      lrun += rs;
      // ---- pack P to LDS (XOR-swizzled [16][64] per-wave tile) ----
#pragma unroll
      for (int n = 0; n < 4; n++) {
        bf16x4 pw;
        pw[0] = (bf16)p[n][0]; pw[1] = (bf16)p[n][1];
        pw[2] = (bf16)p[n][2]; pw[3] = (bf16)p[n][3];
        *(bf16x4*)(Pw + c16 * 64 + (((2 * n + (g >> 1)) ^ (c16 & 7)) * 8) + (g & 1) * 4) = pw;
      }
      // ---- PV: o[q][d] += P[q][s] V^T[d][s]^T ----
      __builtin_amdgcn_s_setprio(1);
#pragma unroll
      for (int ks = 0; ks < 2; ks++) {
        bf16x8 vf[4];
#pragma unroll
        for (int n = 0; n < 4; n++) {
          int drow = n * 16 + c16;
          vf[n] = *(const bf16x8*)((const char*)Vs[cb] + drow * 128 +
                                   (((ks * 4 + g) ^ (drow & 7)) << 4));
        }
        bf16x8 pf = *(const bf16x8*)(Pw + c16 * 64 + (((ks * 4 + g) ^ (c16 & 7)) * 8));
#pragma unroll
        for (int n = 0; n < 4; n++)
          o[n] = MFMA16(pf, vf[n], o[n]);
      }
      __builtin_amdgcn_s_setprio(0);
    }
    if (t + 1 < nt) {
      if (t + 2 < nt) {
        asm volatile("s_waitcnt vmcnt(2)" ::: "memory");  // t+1 done; t+2 in flight
      } else {
        asm volatile("s_waitcnt vmcnt(0)" ::: "memory");
      }
      __builtin_amdgcn_s_barrier();
      __builtin_amdgcn_sched_barrier(0);
    }
  }
  // ---- epilogue ----
  int b = bh >> 4, h = bh & 15;
#pragma unroll
  for (int j = 0; j < 4; j++) {
    float lv = __shfl(lrun, (lane & 48) | (g4 + j));
    float inv = 1.f / lv;
    int t = qlo + g4 + j;
#pragma unroll
    for (int n = 0; n < 4; n++) {
      int col = h * 64 + n * 16 + c16;
      out[((size_t)(b * 2048 + t)) * 1024 + col] = (bf16)(o[n][j] * inv);
    }
  }
}

extern "C" void kernel_launch(void* const* d_in, const int* in_sizes, int n_in,
                              void* d_out, int out_size, void* d_ws, size_t ws_size,
                              hipStream_t stream) {
  const float* x    = (const float*)d_in[0];
  const float* Wqkv = (const float*)d_in[1];
  const float* Wout = (const float*)d_in[2];
  float* outp = (float*)d_out;
  char* ws = (char*)d_ws;
  const size_t MB = 1024 * 1024;
  bf16* xb    = (bf16*)(ws);             // 8 MB [4096][1024]; later reused as attn out
  bf16* wqkvT = (bf16*)(ws + 8 * MB);    // 6 MB [3072][1024]
  bf16* woutT = (bf16*)(ws + 14 * MB);   // 2 MB [1024][1024]
  bf16* qb    = (bf16*)(ws + 16 * MB);   // 8 MB [32][2048][64] (scaled 0.125*log2e)
  bf16* kb    = (bf16*)(ws + 24 * MB);   // 8 MB [32][2048][64]
  bf16* vtb   = (bf16*)(ws + 32 * MB);   // 8 MB [32][64][2048]

  hipLaunchKernelGGL(cast_f32_bf16, dim3(2048), dim3(256), 0, stream,
                     x, xb, 4096 * 1024 / 8);
  hipLaunchKernelGGL(transpose_cast, dim3(96, 32), dim3(32, 8), 0, stream,
                     Wqkv, wqkvT, 1024, 3072);
  hipLaunchKernelGGL(transpose_cast, dim3(32, 32), dim3(32, 8), 0, stream,
                     Wout, woutT, 1024, 1024);
  hipLaunchKernelGGL(gemm256_qkv, dim3(192), dim3(512), 0, stream,
                     xb, wqkvT, qb, kb, vtb);
  hipLaunchKernelGGL(attn, dim3(512), dim3(512), 0, stream,
                     qb, kb, vtb, xb);
  hipLaunchKernelGGL(gemm_out3, dim3(256), dim3(256), 0, stream,
                     xb, woutT, outp);
}

// Round 5
// 132.809 us; speedup vs baseline: 1.1477x; 1.1477x over previous
//
#include <hip/hip_runtime.h>
#include <hip/hip_bf16.h>

typedef __bf16 bf16;
typedef bf16 bf16x4 __attribute__((ext_vector_type(4)));
typedef bf16 bf16x8 __attribute__((ext_vector_type(8)));
typedef float f32x4 __attribute__((ext_vector_type(4)));

#define GLOAD16(g, l) __builtin_amdgcn_global_load_lds( \
    (const __attribute__((address_space(1))) void*)(g),  \
    (__attribute__((address_space(3))) void*)(l), 16, 0, 0)

#define EXP2F(x) __builtin_amdgcn_exp2f(x)
#define MFMA16(a, b, c) __builtin_amdgcn_mfma_f32_16x16x32_bf16(a, b, c, 0, 0, 0)

// ---------------- cast fp32 -> bf16, 8 elems/thread ----------------
__global__ __launch_bounds__(256) void cast_f32_bf16(const float* __restrict__ in,
                                                     bf16* __restrict__ out, int n8) {
  int i = blockIdx.x * 256 + threadIdx.x;
  if (i >= n8) return;
  const float4* p = (const float4*)in + (size_t)i * 2;
  float4 a = p[0], b = p[1];
  bf16x8 o;
  o[0] = (bf16)a.x; o[1] = (bf16)a.y; o[2] = (bf16)a.z; o[3] = (bf16)a.w;
  o[4] = (bf16)b.x; o[5] = (bf16)b.y; o[6] = (bf16)b.z; o[7] = (bf16)b.w;
  ((bf16x8*)out)[i] = o;
}

// ------------- transpose+cast: src[K][N] f32 -> dst[N][K] bf16 -------------
__global__ __launch_bounds__(256) void transpose_cast(const float* __restrict__ src,
                                                      bf16* __restrict__ dst,
                                                      int K, int N) {
  __shared__ float tile[32][33];
  int n0 = blockIdx.x * 32, k0 = blockIdx.y * 32;
  int tx = threadIdx.x, ty = threadIdx.y;  // 32 x 8
#pragma unroll
  for (int i = 0; i < 4; i++)
    tile[ty + 8 * i][tx] = src[(size_t)(k0 + ty + 8 * i) * N + n0 + tx];
  __syncthreads();
#pragma unroll
  for (int i = 0; i < 4; i++)
    dst[(size_t)(n0 + ty + 8 * i) * K + k0 + tx] = (bf16)tile[tx][ty + 8 * i];
}

// ------- GEMM mainloop (round-3 proven): C[128,128] += A * Bt^T, BK=32 -------
__device__ __forceinline__ void gemm_mainloop(const bf16* __restrict__ A,
                                              const bf16* __restrict__ Bt,
                                              int K, int m0, int n0,
                                              f32x4 acc[4][4],
                                              bf16* As, bf16* Bs) {
  int tid = threadIdx.x;
  int lane = tid & 63;
  int wave = tid >> 6;
  int wr = wave >> 1, wc = wave & 1;
  f32x4 z = {0.f, 0.f, 0.f, 0.f};
#pragma unroll
  for (int m = 0; m < 4; m++)
#pragma unroll
    for (int n = 0; n < 4; n++) acc[m][n] = z;
  int c16 = lane & 15;
  int ks8 = (lane >> 4) * 8;
  for (int k0 = 0; k0 < K; k0 += 32) {
#pragma unroll
    for (int i = 0; i < 2; i++) {
      int c = tid + i * 256;
      int r = c >> 2, ks = (c & 3) * 8;
      GLOAD16(A + (size_t)(m0 + r) * K + k0 + ks, As + c * 8);
    }
#pragma unroll
    for (int i = 0; i < 2; i++) {
      int c = tid + i * 256;
      int r = c >> 2, ks = (c & 3) * 8;
      GLOAD16(Bt + (size_t)(n0 + r) * K + k0 + ks, Bs + c * 8);
    }
    __syncthreads();
    bf16x8 af[4], bfr[4];
#pragma unroll
    for (int m = 0; m < 4; m++)
      af[m] = *(const bf16x8*)(As + (wr * 64 + m * 16 + c16) * 32 + ks8);
#pragma unroll
    for (int n = 0; n < 4; n++)
      bfr[n] = *(const bf16x8*)(Bs + (wc * 64 + n * 16 + c16) * 32 + ks8);
#pragma unroll
    for (int m = 0; m < 4; m++)
#pragma unroll
      for (int n = 0; n < 4; n++)
        acc[m][n] = MFMA16(af[m], bfr[n], acc[m][n]);
    __syncthreads();
  }
}

// ---- QKV GEMM: x[4096,1024] @ WqkvT[3072,1024]^T -> q,k scaled / vT scatter ----
__global__ __launch_bounds__(256) void gemm_qkv(const bf16* __restrict__ A,
                                                const bf16* __restrict__ Bt,
                                                bf16* __restrict__ q,
                                                bf16* __restrict__ kk,
                                                bf16* __restrict__ vt) {
  __shared__ bf16 As[128 * 32];
  __shared__ bf16 Bs[128 * 32];
  int m0 = blockIdx.y * 128, n0 = blockIdx.x * 128;
  f32x4 acc[4][4];
  gemm_mainloop(A, Bt, 1024, m0, n0, acc, As, Bs);
  int lane = threadIdx.x & 63;
  int wave = threadIdx.x >> 6;
  int wr = wave >> 1, wc = wave & 1;
  int which = n0 >> 10;
  const float QSCALE = 0.125f * 1.4426950408889634f;
#pragma unroll
  for (int m = 0; m < 4; m++)
#pragma unroll
    for (int n = 0; n < 4; n++)
#pragma unroll
      for (int j = 0; j < 4; j++) {
        int gm = m0 + wr * 64 + m * 16 + (lane >> 4) * 4 + j;
        int gn = n0 + wc * 64 + n * 16 + (lane & 15);
        int rem = gn & 1023;
        int h = rem >> 6, d = rem & 63;
        int b = gm >> 11, t = gm & 2047;
        float v = acc[m][n][j];
        size_t bh = (size_t)(b * 16 + h);
        if (which == 0)      q[(bh * 2048 + t) * 64 + d]  = (bf16)(v * QSCALE);
        else if (which == 1) kk[(bh * 2048 + t) * 64 + d] = (bf16)v;
        else                 vt[(bh * 64 + d) * 2048 + t] = (bf16)v;
      }
}

// ---- final GEMM: attn[4096,1024] @ WoutT[1024,1024]^T -> out fp32 ----
__global__ __launch_bounds__(256) void gemm_out(const bf16* __restrict__ A,
                                                const bf16* __restrict__ Bt,
                                                float* __restrict__ C) {
  __shared__ bf16 As[128 * 32];
  __shared__ bf16 Bs[128 * 32];
  int m0 = blockIdx.y * 128, n0 = blockIdx.x * 128;
  f32x4 acc[4][4];
  gemm_mainloop(A, Bt, 1024, m0, n0, acc, As, Bs);
  int lane = threadIdx.x & 63;
  int wave = threadIdx.x >> 6;
  int wr = wave >> 1, wc = wave & 1;
#pragma unroll
  for (int m = 0; m < 4; m++)
#pragma unroll
    for (int n = 0; n < 4; n++)
#pragma unroll
      for (int j = 0; j < 4; j++) {
        int gm = m0 + wr * 64 + m * 16 + (lane >> 4) * 4 + j;
        int gn = n0 + wc * 64 + n * 16 + (lane & 15);
        C[(size_t)gm * 1024 + gn] = acc[m][n][j];
      }
}

// ---------------- flash attention v5 (softmax/PV pipelined) ----------------
// 512 blocks x 512 threads (8 waves); wave w owns q rows [q0+16w, +16).
// Swapped QK^T; exp2-domain in-register softmax; defer-max. 4 rotating K/V
// buffers, prefetch t+2, counted vmcnt(2), ONE barrier per tile.
// T15-lite: iter t issues QK^T(t) and PV(t-1) MFMAs back-to-back, then runs
// softmax(t) VALU while PV(t-1) drains the matrix pipe. Single per-wave P
// region (read old, then write new: DS ops are in-order per wave).
__global__ __launch_bounds__(512) void attn(const bf16* __restrict__ q,
                                            const bf16* __restrict__ kk,
                                            const bf16* __restrict__ vt,
                                            bf16* __restrict__ out) {
  __shared__ bf16 Ks[4][64 * 64];   // 32 KB (chunk-XOR swizzled)
  __shared__ bf16 Vs[4][64 * 64];   // 32 KB (chunk-XOR swizzled)
  __shared__ bf16 PQ[128 * 64];     // 16 KB: Q staging (prologue) / P tiles
  int tid = threadIdx.x, lane = tid & 63, w = tid >> 6;
  int c16 = lane & 15, g = (lane >> 4) & 3, g4 = g * 4;

  // ---- XCD-aware decode (bijection on 512 blocks) ----
  int id = blockIdx.x;
  int c = id & 7;          // XCD
  int k = id >> 3;         // 0..63 within XCD
  int s = k >> 5;          // 0..1
  int j5 = k & 31;
  int bxi = j5 & 15, b2 = j5 >> 4;
  int bx = s ? (15 - bxi) : bxi;       // pairs (k, k+32) sum to 15
  int bh = 4 * c + 2 * b2 + s;         // 4 bh per XCD (K/V L2-resident)
  int q0 = bx * 128;

  const bf16* qb = q  + (size_t)bh * 2048 * 64;
  const bf16* kb = kk + (size_t)bh * 2048 * 64;
  const bf16* vb = vt + (size_t)bh * 64 * 2048;
  int nt = 2 * bx + 2;

  // ---- prologue: stage Q[128][64] + K/V tiles 0,1 ----
#pragma unroll
  for (int i = 0; i < 2; i++) {
    int cc = tid + i * 512;
    int r = cc >> 3, ds = (cc & 7) * 8;
    GLOAD16(qb + (size_t)(q0 + r) * 64 + ds, PQ + cc * 8);
  }
  {
    int r = tid >> 3, p = tid & 7;
    GLOAD16(kb + (size_t)r * 64 + ((p ^ (r & 7)) * 8), Ks[0] + tid * 8);
    GLOAD16(vb + (size_t)r * 2048 + ((p ^ (r & 7)) * 8), Vs[0] + tid * 8);
    GLOAD16(kb + (size_t)(64 + r) * 64 + ((p ^ (r & 7)) * 8), Ks[1] + tid * 8);
    GLOAD16(vb + (size_t)r * 2048 + 64 + ((p ^ (r & 7)) * 8), Vs[1] + tid * 8);
  }
  __syncthreads();   // drains all prologue staging
  bf16x8 qf[2];      // B-operand frag: Q[q0+16w+c16][ks*32+g*8 ..]
#pragma unroll
  for (int ks = 0; ks < 2; ks++)
    qf[ks] = *(const bf16x8*)(PQ + (w * 16 + c16) * 64 + ks * 32 + g * 8);
  __syncthreads();   // all waves done reading Q (PQ becomes P storage)

  f32x4 o[4];
  float mrun = -__builtin_inff(), lrun = 0.f;
  {
    f32x4 z = {0.f, 0.f, 0.f, 0.f};
#pragma unroll
    for (int n = 0; n < 4; n++) o[n] = z;
  }
  int qlo = q0 + w * 16;
  int qr = qlo + c16;
  int ta = ((qlo + 15) >> 6) + 1;   // tiles this wave computes QK^T for (<= nt)
  bf16* Pw = PQ + w * 1024;         // 16x64 per-wave P tile

  for (int t = 0; t < nt; ++t) {
    int s0 = t * 64;
    if (t + 2 < nt) {              // prefetch tile t+2
      int sn = s0 + 128;
      int r = tid >> 3, p = tid & 7;
      int nb = (t + 2) & 3;
      GLOAD16(kb + (size_t)(sn + r) * 64 + ((p ^ (r & 7)) * 8), Ks[nb] + tid * 8);
      GLOAD16(vb + (size_t)r * 2048 + sn + ((p ^ (r & 7)) * 8), Vs[nb] + tid * 8);
    }
    int cb = t & 3, pb = (t + 3) & 3;
    f32x4 S[4];
    // ---- QK^T(t): S^T = mfma(K, Q); lane holds S[q=c16][s=n*16+g4+r] ----
    if (t < ta) {
      f32x4 z = {0.f, 0.f, 0.f, 0.f};
#pragma unroll
      for (int n = 0; n < 4; n++) S[n] = z;
      __builtin_amdgcn_s_setprio(1);
#pragma unroll
      for (int ks = 0; ks < 2; ks++) {
        bf16x8 kf[4];
#pragma unroll
        for (int n = 0; n < 4; n++) {
          int srow = n * 16 + c16;
          kf[n] = *(const bf16x8*)((const char*)Ks[cb] + srow * 128 +
                                   (((ks * 4 + g) ^ (srow & 7)) << 4));
        }
#pragma unroll
        for (int n = 0; n < 4; n++)
          S[n] = MFMA16(kf[n], qf[ks], S[n]);
      }
      __builtin_amdgcn_s_setprio(0);
    }
    // ---- PV(t-1): fills MFMA pipe while softmax(t) runs on VALU ----
    if (t >= 1 && t - 1 < ta) {
      __builtin_amdgcn_s_setprio(1);
#pragma unroll
      for (int ks = 0; ks < 2; ks++) {
        bf16x8 vf[4];
#pragma unroll
        for (int n = 0; n < 4; n++) {
          int drow = n * 16 + c16;
          vf[n] = *(const bf16x8*)((const char*)Vs[pb] + drow * 128 +
                                   (((ks * 4 + g) ^ (drow & 7)) << 4));
        }
        bf16x8 pf = *(const bf16x8*)(Pw + c16 * 64 + (((ks * 4 + g) ^ (c16 & 7)) * 8));
#pragma unroll
        for (int n = 0; n < 4; n++)
          o[n] = MFMA16(pf, vf[n], o[n]);
      }
      __builtin_amdgcn_s_setprio(0);
    }
    // ---- softmax(t) + P write ----
    if (t < ta) {
      if (s0 + 63 > qlo) {   // diag tiles only
#pragma unroll
        for (int n = 0; n < 4; n++)
#pragma unroll
          for (int r = 0; r < 4; r++)
            if (s0 + n * 16 + g4 + r > qr) S[n][r] = -__builtin_inff();
      }
      float tm = fmaxf(fmaxf(fmaxf(S[0][0], S[0][1]), fmaxf(S[0][2], S[0][3])),
                       fmaxf(fmaxf(S[1][0], S[1][1]), fmaxf(S[1][2], S[1][3])));
      tm = fmaxf(tm, fmaxf(fmaxf(fmaxf(S[2][0], S[2][1]), fmaxf(S[2][2], S[2][3])),
                           fmaxf(fmaxf(S[3][0], S[3][1]), fmaxf(S[3][2], S[3][3]))));
      tm = fmaxf(tm, __shfl_xor(tm, 16));
      tm = fmaxf(tm, __shfl_xor(tm, 32));
      if (!__all(tm <= mrun + 8.f)) {   // defer-max rescale (rare)
        float mnew = fmaxf(mrun, tm);
        float corr = EXP2F(mrun - mnew);
        lrun *= corr;
        mrun = mnew;
#pragma unroll
        for (int j = 0; j < 4; j++) {
          float cj = __shfl(corr, (lane & 48) | (g4 + j));
#pragma unroll
          for (int n = 0; n < 4; n++) o[n][j] *= cj;
        }
      }
      float p[4][4];
      float rs = 0.f;
#pragma unroll
      for (int n = 0; n < 4; n++)
#pragma unroll
        for (int r = 0; r < 4; r++) {
          p[n][r] = EXP2F(S[n][r] - mrun);
          rs += p[n][r];
        }
      rs += __shfl_xor(rs, 16);
      rs += __shfl_xor(rs, 32);
      lrun += rs;
#pragma unroll
      for (int n = 0; n < 4; n++) {
        bf16x4 pw;
        pw[0] = (bf16)p[n][0]; pw[1] = (bf16)p[n][1];
        pw[2] = (bf16)p[n][2]; pw[3] = (bf16)p[n][3];
        *(bf16x4*)(Pw + c16 * 64 + (((2 * n + (g >> 1)) ^ (c16 & 7)) * 8) + (g & 1) * 4) = pw;
      }
    }
    if (t + 1 < nt) {
      if (t + 2 < nt) {
        asm volatile("s_waitcnt vmcnt(2)" ::: "memory");  // t+1 resident; t+2 in flight
      } else {
        asm volatile("s_waitcnt vmcnt(0)" ::: "memory");
      }
      __builtin_amdgcn_s_barrier();
      __builtin_amdgcn_sched_barrier(0);
    }
  }
  // ---- drain: PV(nt-1) for waves whose last tile was computed in iter nt-1 ----
  if (ta == nt) {
    int pb = (nt + 3) & 3;
    __builtin_amdgcn_s_setprio(1);
#pragma unroll
    for (int ks = 0; ks < 2; ks++) {
      bf16x8 vf[4];
#pragma unroll
      for (int n = 0; n < 4; n++) {
        int drow = n * 16 + c16;
        vf[n] = *(const bf16x8*)((const char*)Vs[pb] + drow * 128 +
                                 (((ks * 4 + g) ^ (drow & 7)) << 4));
      }
      bf16x8 pf = *(const bf16x8*)(Pw + c16 * 64 + (((ks * 4 + g) ^ (c16 & 7)) * 8));
#pragma unroll
      for (int n = 0; n < 4; n++)
        o[n] = MFMA16(pf, vf[n], o[n]);
    }
    __builtin_amdgcn_s_setprio(0);
  }
  // ---- epilogue: o row q = qlo+g4+j, col d = n*16+c16 ----
  int b = bh >> 4, h = bh & 15;
#pragma unroll
  for (int j = 0; j < 4; j++) {
    float lv = __shfl(lrun, (lane & 48) | (g4 + j));
    float inv = 1.f / lv;
    int t = qlo + g4 + j;
#pragma unroll
    for (int n = 0; n < 4; n++) {
      int col = h * 64 + n * 16 + c16;
      out[((size_t)(b * 2048 + t)) * 1024 + col] = (bf16)(o[n][j] * inv);
    }
  }
}

extern "C" void kernel_launch(void* const* d_in, const int* in_sizes, int n_in,
                              void* d_out, int out_size, void* d_ws, size_t ws_size,
                              hipStream_t stream) {
  const float* x    = (const float*)d_in[0];
  const float* Wqkv = (const float*)d_in[1];
  const float* Wout = (const float*)d_in[2];
  float* outp = (float*)d_out;
  char* ws = (char*)d_ws;
  const size_t MB = 1024 * 1024;
  bf16* xb    = (bf16*)(ws);             // 8 MB [4096][1024]; later reused as attn out
  bf16* wqkvT = (bf16*)(ws + 8 * MB);    // 6 MB [3072][1024]
  bf16* woutT = (bf16*)(ws + 14 * MB);   // 2 MB [1024][1024]
  bf16* qb    = (bf16*)(ws + 16 * MB);   // 8 MB [32][2048][64] (scaled 0.125*log2e)
  bf16* kb    = (bf16*)(ws + 24 * MB);   // 8 MB [32][2048][64]
  bf16* vtb   = (bf16*)(ws + 32 * MB);   // 8 MB [32][64][2048]

  hipLaunchKernelGGL(cast_f32_bf16, dim3(2048), dim3(256), 0, stream,
                     x, xb, 4096 * 1024 / 8);
  hipLaunchKernelGGL(transpose_cast, dim3(96, 32), dim3(32, 8), 0, stream,
                     Wqkv, wqkvT, 1024, 3072);
  hipLaunchKernelGGL(transpose_cast, dim3(32, 32), dim3(32, 8), 0, stream,
                     Wout, woutT, 1024, 1024);
  hipLaunchKernelGGL(gemm_qkv, dim3(24, 32), dim3(256), 0, stream,
                     xb, wqkvT, qb, kb, vtb);
  hipLaunchKernelGGL(attn, dim3(512), dim3(512), 0, stream,
                     qb, kb, vtb, xb);
  hipLaunchKernelGGL(gemm_out, dim3(8, 32), dim3(256), 0, stream,
                     xb, woutT, outp);
}

// Round 6
// 119.008 us; speedup vs baseline: 1.2808x; 1.1160x over previous
//
#include <hip/hip_runtime.h>
#include <hip/hip_bf16.h>

typedef __bf16 bf16;
typedef bf16 bf16x4 __attribute__((ext_vector_type(4)));
typedef bf16 bf16x8 __attribute__((ext_vector_type(8)));
typedef float f32x4 __attribute__((ext_vector_type(4)));

#define GLOAD16(g, l) __builtin_amdgcn_global_load_lds( \
    (const __attribute__((address_space(1))) void*)(g),  \
    (__attribute__((address_space(3))) void*)(l), 16, 0, 0)

#define EXP2F(x) __builtin_amdgcn_exp2f(x)
#define MFMA16(a, b, c) __builtin_amdgcn_mfma_f32_16x16x32_bf16(a, b, c, 0, 0, 0)

// ---------------- cast fp32 -> bf16, 8 elems/thread ----------------
__global__ __launch_bounds__(256) void cast_f32_bf16(const float* __restrict__ in,
                                                     bf16* __restrict__ out, int n8) {
  int i = blockIdx.x * 256 + threadIdx.x;
  if (i >= n8) return;
  const float4* p = (const float4*)in + (size_t)i * 2;
  float4 a = p[0], b = p[1];
  bf16x8 o;
  o[0] = (bf16)a.x; o[1] = (bf16)a.y; o[2] = (bf16)a.z; o[3] = (bf16)a.w;
  o[4] = (bf16)b.x; o[5] = (bf16)b.y; o[6] = (bf16)b.z; o[7] = (bf16)b.w;
  ((bf16x8*)out)[i] = o;
}

// ------------- transpose+cast: src[K][N] f32 -> dst[N][K] bf16 -------------
__global__ __launch_bounds__(256) void transpose_cast(const float* __restrict__ src,
                                                      bf16* __restrict__ dst,
                                                      int K, int N) {
  __shared__ float tile[32][33];
  int n0 = blockIdx.x * 32, k0 = blockIdx.y * 32;
  int tx = threadIdx.x, ty = threadIdx.y;  // 32 x 8
#pragma unroll
  for (int i = 0; i < 4; i++)
    tile[ty + 8 * i][tx] = src[(size_t)(k0 + ty + 8 * i) * N + n0 + tx];
  __syncthreads();
#pragma unroll
  for (int i = 0; i < 4; i++)
    dst[(size_t)(n0 + ty + 8 * i) * K + k0 + tx] = (bf16)tile[tx][ty + 8 * i];
}

// ---- GEMM mainloop BK=64: C[128,128] += A[.,K] * Bt[.,K]^T ----
// 4 waves (2x2), wave tile 64x64, 16 MFMA x 2 k-halves per step. LDS rows
// 128 B, chunk-XOR swizzle (ch ^= row&7): inverse applied on global source
// (linear LDS dest, rule #21), same XOR on fragment reads -> bank-spread.
__device__ __forceinline__ void gemm_mainloop64(const bf16* __restrict__ A,
                                                const bf16* __restrict__ Bt,
                                                int K, int m0, int n0,
                                                f32x4 acc[4][4],
                                                bf16* As, bf16* Bs) {
  int tid = threadIdx.x;
  int lane = tid & 63;
  int wave = tid >> 6;
  int wr = wave >> 1, wc = wave & 1;
  int c16 = lane & 15, g = lane >> 4;
  f32x4 z = {0.f, 0.f, 0.f, 0.f};
#pragma unroll
  for (int m = 0; m < 4; m++)
#pragma unroll
    for (int n = 0; n < 4; n++) acc[m][n] = z;
  for (int k0 = 0; k0 < K; k0 += 64) {
#pragma unroll
    for (int i = 0; i < 4; i++) {
      int cc = tid + i * 256;          // 0..1023 chunks of 16B
      int r = cc >> 3, ch = cc & 7;
      int sc = ch ^ (r & 7);
      GLOAD16(A + (size_t)(m0 + r) * K + k0 + sc * 8, As + cc * 8);
    }
#pragma unroll
    for (int i = 0; i < 4; i++) {
      int cc = tid + i * 256;
      int r = cc >> 3, ch = cc & 7;
      int sc = ch ^ (r & 7);
      GLOAD16(Bt + (size_t)(n0 + r) * K + k0 + sc * 8, Bs + cc * 8);
    }
    __syncthreads();
#pragma unroll
    for (int h = 0; h < 2; h++) {
      bf16x8 af[4], bfr[4];
#pragma unroll
      for (int m = 0; m < 4; m++) {
        int ar = wr * 64 + m * 16 + c16;
        af[m] = *(const bf16x8*)((const char*)As + ar * 128 + (((h * 4 + g) ^ (ar & 7)) << 4));
      }
#pragma unroll
      for (int n = 0; n < 4; n++) {
        int br = wc * 64 + n * 16 + c16;
        bfr[n] = *(const bf16x8*)((const char*)Bs + br * 128 + (((h * 4 + g) ^ (br & 7)) << 4));
      }
      __builtin_amdgcn_s_setprio(1);
#pragma unroll
      for (int m = 0; m < 4; m++)
#pragma unroll
        for (int n = 0; n < 4; n++)
          acc[m][n] = MFMA16(af[m], bfr[n], acc[m][n]);
      __builtin_amdgcn_s_setprio(0);
    }
    __syncthreads();
  }
}

// ---- QKV GEMM: x[4096,1024] @ WqkvT[3072,1024]^T -> q,k scaled / vT ----
// grid 768 = 8 XCD x 96; XCD owns 3 bn-cols (768 KB B-slice, L2-resident).
__global__ __launch_bounds__(256) void gemm_qkv(const bf16* __restrict__ A,
                                                const bf16* __restrict__ Bt,
                                                bf16* __restrict__ q,
                                                bf16* __restrict__ kk,
                                                bf16* __restrict__ vt) {
  __shared__ bf16 As[128 * 64];
  __shared__ bf16 Bs[128 * 64];
  int id = blockIdx.x;
  int xc = id & 7, k = id >> 3;            // k in [0,96)
  int bn = xc * 3 + (k % 3), bm = k / 3;   // bijective: bn [0,24), bm [0,32)
  int m0 = bm * 128, n0 = bn * 128;
  f32x4 acc[4][4];
  gemm_mainloop64(A, Bt, 1024, m0, n0, acc, As, Bs);
  int lane = threadIdx.x & 63;
  int wave = threadIdx.x >> 6;
  int wr = wave >> 1, wc = wave & 1;
  int c16 = lane & 15, g = lane >> 4;
  int which = n0 >> 10;
  const float QSCALE = 0.125f * 1.4426950408889634f;
  if (which == 2) {
    // vt[bh][d][t]: the 4 j-values are 4 consecutive t -> vectorized 8B store
#pragma unroll
    for (int m = 0; m < 4; m++)
#pragma unroll
      for (int n = 0; n < 4; n++) {
        int gm0 = m0 + wr * 64 + m * 16 + g * 4;
        int gn = n0 + wc * 64 + n * 16 + c16;
        int rem = gn & 1023, h = rem >> 6, d = rem & 63;
        int b = gm0 >> 11, t0 = gm0 & 2047;
        size_t bh = (size_t)(b * 16 + h);
        bf16x4 pv;
        pv[0] = (bf16)acc[m][n][0]; pv[1] = (bf16)acc[m][n][1];
        pv[2] = (bf16)acc[m][n][2]; pv[3] = (bf16)acc[m][n][3];
        *(bf16x4*)(vt + (bh * 64 + d) * 2048 + t0) = pv;
      }
  } else {
#pragma unroll
    for (int m = 0; m < 4; m++)
#pragma unroll
      for (int n = 0; n < 4; n++)
#pragma unroll
        for (int j = 0; j < 4; j++) {
          int gm = m0 + wr * 64 + m * 16 + g * 4 + j;
          int gn = n0 + wc * 64 + n * 16 + c16;
          int rem = gn & 1023, h = rem >> 6, d = rem & 63;
          int b = gm >> 11, t = gm & 2047;
          float v = acc[m][n][j];
          size_t bh = (size_t)(b * 16 + h);
          if (which == 0) q[(bh * 2048 + t) * 64 + d]  = (bf16)(v * QSCALE);
          else            kk[(bh * 2048 + t) * 64 + d] = (bf16)v;
        }
  }
}

// ---- final GEMM: attn[4096,1024] @ WoutT[1024,1024]^T -> out fp32 ----
// grid 256 = 8 XCD x 32; XCD owns 1 bn-col (256 KB B-slice, L2-resident).
__global__ __launch_bounds__(256) void gemm_out(const bf16* __restrict__ A,
                                                const bf16* __restrict__ Bt,
                                                float* __restrict__ C) {
  __shared__ bf16 As[128 * 64];
  __shared__ bf16 Bs[128 * 64];
  int id = blockIdx.x;
  int bn = id & 7, bm = id >> 3;
  int m0 = bm * 128, n0 = bn * 128;
  f32x4 acc[4][4];
  gemm_mainloop64(A, Bt, 1024, m0, n0, acc, As, Bs);
  int lane = threadIdx.x & 63;
  int wave = threadIdx.x >> 6;
  int wr = wave >> 1, wc = wave & 1;
#pragma unroll
  for (int m = 0; m < 4; m++)
#pragma unroll
    for (int n = 0; n < 4; n++)
#pragma unroll
      for (int j = 0; j < 4; j++) {
        int gm = m0 + wr * 64 + m * 16 + (lane >> 4) * 4 + j;
        int gn = n0 + wc * 64 + n * 16 + (lane & 15);
        C[(size_t)gm * 1024 + gn] = acc[m][n][j];
      }
}

// ---------------- flash attention v6 (2-buf, 3 blocks/CU) ----------------
// 512 blocks x 512 threads (8 waves); wave w owns q rows [q0+16w, +16).
// Straight-line v4 compute (pipelined PV was neutral, reverted). 2 K/V
// buffers: prefetch t+1 issued BEFORE compute(t) (~1700 cyc covers L2
// latency), vmcnt(0)+barrier at iter end. LDS 48 KB -> 3 blocks/CU.
__global__ __launch_bounds__(512) void attn(const bf16* __restrict__ q,
                                            const bf16* __restrict__ kk,
                                            const bf16* __restrict__ vt,
                                            bf16* __restrict__ out) {
  __shared__ bf16 Ks[2][64 * 64];   // 16 KB (chunk-XOR swizzled)
  __shared__ bf16 Vs[2][64 * 64];   // 16 KB (chunk-XOR swizzled)
  __shared__ bf16 PQ[128 * 64];     // 16 KB: Q staging (prologue) / P tiles
  int tid = threadIdx.x, lane = tid & 63, w = tid >> 6;
  int c16 = lane & 15, g = (lane >> 4) & 3, g4 = g * 4;

  // ---- XCD-aware decode (bijection on 512 blocks) ----
  int id = blockIdx.x;
  int c = id & 7;          // XCD
  int k = id >> 3;         // 0..63 within XCD
  int s = k >> 5;          // 0..1
  int j5 = k & 31;
  int bxi = j5 & 15, b2 = j5 >> 4;
  int bx = s ? (15 - bxi) : bxi;       // pairs sum to 15 (load balance)
  int bh = 4 * c + 2 * b2 + s;         // 4 bh per XCD (K/V L2-resident)
  int q0 = bx * 128;

  const bf16* qb = q  + (size_t)bh * 2048 * 64;
  const bf16* kb = kk + (size_t)bh * 2048 * 64;
  const bf16* vb = vt + (size_t)bh * 64 * 2048;
  int nt = 2 * bx + 2;

  // ---- prologue: stage Q[128][64] + K/V tile 0 ----
#pragma unroll
  for (int i = 0; i < 2; i++) {
    int cc = tid + i * 512;
    int r = cc >> 3, ds = (cc & 7) * 8;
    GLOAD16(qb + (size_t)(q0 + r) * 64 + ds, PQ + cc * 8);
  }
  {
    int r = tid >> 3, p = tid & 7;
    GLOAD16(kb + (size_t)r * 64 + ((p ^ (r & 7)) * 8), Ks[0] + tid * 8);
    GLOAD16(vb + (size_t)r * 2048 + ((p ^ (r & 7)) * 8), Vs[0] + tid * 8);
  }
  __syncthreads();   // drains all prologue staging
  bf16x8 qf[2];      // B-operand frag: Q[q0+16w+c16][ks*32+g*8 ..]
#pragma unroll
  for (int ks = 0; ks < 2; ks++)
    qf[ks] = *(const bf16x8*)(PQ + (w * 16 + c16) * 64 + ks * 32 + g * 8);
  __syncthreads();   // all waves done reading Q (PQ becomes P storage)

  f32x4 o[4];
  float mrun = -__builtin_inff(), lrun = 0.f;
  {
    f32x4 z = {0.f, 0.f, 0.f, 0.f};
#pragma unroll
    for (int n = 0; n < 4; n++) o[n] = z;
  }
  int qlo = q0 + w * 16;
  int qr = qlo + c16;
  bf16* Pw = PQ + w * 1024;        // 16x64 per-wave P tile

  for (int t = 0; t < nt; ++t) {
    int s0 = t * 64;
    int cb = t & 1;
    if (t + 1 < nt) {              // prefetch t+1 into other buffer
      int sn = s0 + 64;
      int r = tid >> 3, p = tid & 7;
      GLOAD16(kb + (size_t)(sn + r) * 64 + ((p ^ (r & 7)) * 8), Ks[cb ^ 1] + tid * 8);
      GLOAD16(vb + (size_t)r * 2048 + sn + ((p ^ (r & 7)) * 8), Vs[cb ^ 1] + tid * 8);
    }
    if (s0 <= qlo + 15) {   // wave-uniform causal skip
      // ---- QK^T: S^T = mfma(K, Q); lane holds S[q=c16][s=n*16+g4+r] ----
      f32x4 S[4];
      {
        f32x4 z = {0.f, 0.f, 0.f, 0.f};
#pragma unroll
        for (int n = 0; n < 4; n++) S[n] = z;
      }
      __builtin_amdgcn_s_setprio(1);
#pragma unroll
      for (int ks = 0; ks < 2; ks++) {
        bf16x8 kf[4];
#pragma unroll
        for (int n = 0; n < 4; n++) {
          int srow = n * 16 + c16;
          kf[n] = *(const bf16x8*)((const char*)Ks[cb] + srow * 128 +
                                   (((ks * 4 + g) ^ (srow & 7)) << 4));
        }
#pragma unroll
        for (int n = 0; n < 4; n++)
          S[n] = MFMA16(kf[n], qf[ks], S[n]);
      }
      __builtin_amdgcn_s_setprio(0);
      // ---- causal mask (diag tiles only) ----
      if (s0 + 63 > qlo) {
#pragma unroll
        for (int n = 0; n < 4; n++)
#pragma unroll
          for (int r = 0; r < 4; r++)
            if (s0 + n * 16 + g4 + r > qr) S[n][r] = -__builtin_inff();
      }
      // ---- online softmax (exp2 domain), defer-max ----
      float tm = fmaxf(fmaxf(fmaxf(S[0][0], S[0][1]), fmaxf(S[0][2], S[0][3])),
                       fmaxf(fmaxf(S[1][0], S[1][1]), fmaxf(S[1][2], S[1][3])));
      tm = fmaxf(tm, fmaxf(fmaxf(fmaxf(S[2][0], S[2][1]), fmaxf(S[2][2], S[2][3])),
                           fmaxf(fmaxf(S[3][0], S[3][1]), fmaxf(S[3][2], S[3][3]))));
      tm = fmaxf(tm, __shfl_xor(tm, 16));
      tm = fmaxf(tm, __shfl_xor(tm, 32));
      if (!__all(tm <= mrun + 8.f)) {   // rescale (rare after first tile)
        float mnew = fmaxf(mrun, tm);
        float corr = EXP2F(mrun - mnew);
        lrun *= corr;
        mrun = mnew;
#pragma unroll
        for (int j = 0; j < 4; j++) {
          float cj = __shfl(corr, (lane & 48) | (g4 + j));
#pragma unroll
          for (int n = 0; n < 4; n++) o[n][j] *= cj;
        }
      }
      float p[4][4];
      float rs = 0.f;
#pragma unroll
      for (int n = 0; n < 4; n++)
#pragma unroll
        for (int r = 0; r < 4; r++) {
          p[n][r] = EXP2F(S[n][r] - mrun);
          rs += p[n][r];
        }
      rs += __shfl_xor(rs, 16);
      rs += __shfl_xor(rs, 32);
      lrun += rs;
      // ---- pack P to LDS (XOR-swizzled [16][64] per-wave tile) ----
#pragma unroll
      for (int n = 0; n < 4; n++) {
        bf16x4 pw;
        pw[0] = (bf16)p[n][0]; pw[1] = (bf16)p[n][1];
        pw[2] = (bf16)p[n][2]; pw[3] = (bf16)p[n][3];
        *(bf16x4*)(Pw + c16 * 64 + (((2 * n + (g >> 1)) ^ (c16 & 7)) * 8) + (g & 1) * 4) = pw;
      }
      // ---- PV: o[q][d] += P[q][s] V^T[d][s]^T ----
      __builtin_amdgcn_s_setprio(1);
#pragma unroll
      for (int ks = 0; ks < 2; ks++) {
        bf16x8 vf[4];
#pragma unroll
        for (int n = 0; n < 4; n++) {
          int drow = n * 16 + c16;
          vf[n] = *(const bf16x8*)((const char*)Vs[cb] + drow * 128 +
                                   (((ks * 4 + g) ^ (drow & 7)) << 4));
        }
        bf16x8 pf = *(const bf16x8*)(Pw + c16 * 64 + (((ks * 4 + g) ^ (c16 & 7)) * 8));
#pragma unroll
        for (int n = 0; n < 4; n++)
          o[n] = MFMA16(pf, vf[n], o[n]);
      }
      __builtin_amdgcn_s_setprio(0);
    }
    if (t + 1 < nt) {
      asm volatile("s_waitcnt vmcnt(0)" ::: "memory");  // t+1 staged (issued pre-compute)
      __builtin_amdgcn_s_barrier();
      __builtin_amdgcn_sched_barrier(0);
    }
  }
  // ---- epilogue: o row q = qlo+g4+j, col d = n*16+c16 ----
  int b = bh >> 4, h = bh & 15;
#pragma unroll
  for (int j = 0; j < 4; j++) {
    float lv = __shfl(lrun, (lane & 48) | (g4 + j));
    float inv = 1.f / lv;
    int t = qlo + g4 + j;
#pragma unroll
    for (int n = 0; n < 4; n++) {
      int col = h * 64 + n * 16 + c16;
      out[((size_t)(b * 2048 + t)) * 1024 + col] = (bf16)(o[n][j] * inv);
    }
  }
}

extern "C" void kernel_launch(void* const* d_in, const int* in_sizes, int n_in,
                              void* d_out, int out_size, void* d_ws, size_t ws_size,
                              hipStream_t stream) {
  const float* x    = (const float*)d_in[0];
  const float* Wqkv = (const float*)d_in[1];
  const float* Wout = (const float*)d_in[2];
  float* outp = (float*)d_out;
  char* ws = (char*)d_ws;
  const size_t MB = 1024 * 1024;
  bf16* xb    = (bf16*)(ws);             // 8 MB [4096][1024]; later reused as attn out
  bf16* wqkvT = (bf16*)(ws + 8 * MB);    // 6 MB [3072][1024]
  bf16* woutT = (bf16*)(ws + 14 * MB);   // 2 MB [1024][1024]
  bf16* qb    = (bf16*)(ws + 16 * MB);   // 8 MB [32][2048][64] (scaled 0.125*log2e)
  bf16* kb    = (bf16*)(ws + 24 * MB);   // 8 MB [32][2048][64]
  bf16* vtb   = (bf16*)(ws + 32 * MB);   // 8 MB [32][64][2048]

  hipLaunchKernelGGL(cast_f32_bf16, dim3(2048), dim3(256), 0, stream,
                     x, xb, 4096 * 1024 / 8);
  hipLaunchKernelGGL(transpose_cast, dim3(96, 32), dim3(32, 8), 0, stream,
                     Wqkv, wqkvT, 1024, 3072);
  hipLaunchKernelGGL(transpose_cast, dim3(32, 32), dim3(32, 8), 0, stream,
                     Wout, woutT, 1024, 1024);
  hipLaunchKernelGGL(gemm_qkv, dim3(768), dim3(256), 0, stream,
                     xb, wqkvT, qb, kb, vtb);
  hipLaunchKernelGGL(attn, dim3(512), dim3(512), 0, stream,
                     qb, kb, vtb, xb);
  hipLaunchKernelGGL(gemm_out, dim3(256), dim3(256), 0, stream,
                     xb, woutT, outp);
}